// Round 4
// baseline (234.218 us; speedup 1.0000x reference)
//
#include <hip/hip_runtime.h>
#include <hip/hip_bf16.h>

// Conv2d 3x3 s1p1: x(32,128,56,56) f32, w(256,128,3,3) f32, bias(256) -> (32,256,56,56) f32.
// R4: FUSED kernel. Block = (n, y0, co-half). B-slab (3 input rows x 58 cols x 128 ci, bf16,
// seg-XOR-swizzled [pix][ci]) staged ONCE per block via in-LDS transpose from NCHW fp32;
// K-loop stages only A (Wt[tap][co][ci], global_load_lds 16B) per tap-step. No xpad pre-pass.

#define CIN   128
#define HH    56
#define WW    56
#define COUT  256
#define HW    3136
#define NIMG  32
#define SLABP 182                       // 3*58 rows + 8 overrun pad (dead-col reads stay in-bounds)
#define SLAB_BYTES (SLABP * 256)        // 46592
#define ALDS_BYTES 32768
#define WT_PLANE   (COUT * CIN * 2)     // 65536 B per tap

typedef __bf16 bf16x8 __attribute__((ext_vector_type(8)));
typedef float  f32x4  __attribute__((ext_vector_type(4)));

#define GLD16(g, l) __builtin_amdgcn_global_load_lds( \
    (const __attribute__((address_space(1))) void*)(g), \
    (__attribute__((address_space(3))) void*)(l), 16, 0, 0)

// ---- tiny pre-pass: w (co,ci,3,3) f32 -> Wt[tap][co][ci] bf16. 1152 blocks, coalesced writes.
__global__ __launch_bounds__(256) void prep_w(const float* __restrict__ w,
                                              __hip_bfloat16* __restrict__ wt) {
    const int L  = blockIdx.x * 256 + threadIdx.x;   // < 294912
    const int ci = L & 127;
    const int co = (L >> 7) & 255;
    const int tp = L >> 15;
    wt[L] = __float2bfloat16(w[(co * CIN + ci) * 9 + tp]);
}

__global__ __launch_bounds__(256) void conv_fused(
    const float* __restrict__ xin,
    const char*  __restrict__ wtb,
    const float* __restrict__ bias,
    float* __restrict__ out)
{
    // slab: [pix][ci] bf16, pix = rr*58 + (x_in+1); 16B seg s of row P holds ci-seg s^(P&15)
    __shared__ __align__(16) char slab[SLAB_BYTES];
    __shared__ __align__(16) char Alds[ALDS_BYTES];

    const int tid  = threadIdx.x;
    const int l    = tid & 63;
    const int wv   = tid >> 6;
    const int wm   = wv & 1;
    const int wn   = wv >> 1;
    const int l15  = l & 15;
    const int quad = l >> 4;

    const int idx = blockIdx.x;                 // 2 co * 32 n * 56 y0 = 3584
    const int cob = idx & 1;
    const int n   = (idx >> 1) & 31;
    const int y0  = idx >> 6;
    const int cobase = cob * 128;

    // ---- zero slab (halo + pad stay zero) ----
    #pragma unroll
    for (int i = 0; i < 12; ++i) {
        const int z = tid + 256 * i;
        if (z < SLAB_BYTES / 16) ((uint4*)slab)[z] = make_uint4(0, 0, 0, 0);
    }

    // ---- A staging offsets (R3-verified pattern): chunk c = wv*8+j covers rows 4c..4c+3 ----
    unsigned aoff[8];
    #pragma unroll
    for (int j = 0; j < 8; ++j) {
        const int c    = wv * 8 + j;
        const int row  = 4 * c + (l >> 4);
        const int gseg = (l & 15) ^ (row & 15);
        aoff[j] = (unsigned)((cobase + row) * 256 + gseg * 16);
    }

    __syncthreads();   // zeros before interior fill

    // ---- fill slab interior: coalesced f32 reads along x, transposed bf16 ds_writes ----
    // thread = (ci = tid&127, half = tid>>7); banks: 64 consecutive ci -> 2 lanes/bank (free)
    {
        const int ci   = tid & 127;
        const int half = tid >> 7;
        const float* xplane = xin + (size_t)(n * CIN + ci) * HW;
        #pragma unroll
        for (int rr = 0; rr < 3; ++rr) {
            const int gy = y0 - 1 + rr;                    // block-uniform branch
            if (gy < 0 || gy >= HH) continue;
            const float4* src = (const float4*)(xplane + gy * WW + half * 28);
            #pragma unroll
            for (int j = 0; j < 7; ++j) {
                const float4 v = src[j];
                const int P0 = rr * 58 + 1 + half * 28 + 4 * j;
                const float vv[4] = {v.x, v.y, v.z, v.w};
                #pragma unroll
                for (int k = 0; k < 4; ++k) {
                    const int P = P0 + k;
                    const int a = P * 256 + ((((ci >> 3) ^ (P & 15)) << 4) | ((ci & 7) << 1));
                    *(unsigned short*)(slab + a) = (unsigned short)(__float_as_uint(vv[k]) >> 16);
                }
            }
        }
    }

    f32x4 acc[4][2];
    #pragma unroll
    for (int i = 0; i < 4; ++i) {
        acc[i][0] = (f32x4){0.f, 0.f, 0.f, 0.f};
        acc[i][1] = (f32x4){0.f, 0.f, 0.f, 0.f};
    }

    // ---- K-loop: 9 taps, stage only A (32 KB, L2-hot) per step ----
    #pragma unroll
    for (int t = 0; t < 9; ++t) {
        const int r = t / 3;
        const int s = t - 3 * r;
        const unsigned wo = (unsigned)(t * WT_PLANE);

        __syncthreads();   // t=0: slab writes visible; t>0: A-frag reads done before overwrite
        #pragma unroll
        for (int j = 0; j < 8; ++j)
            GLD16(wtb + wo + aoff[j], Alds + (wv * 8 + j) * 1024);
        __syncthreads();   // A drained

        #pragma unroll
        for (int kg = 0; kg < 4; ++kg) {
            bf16x8 af[4], bfr[2];
            #pragma unroll
            for (int mt = 0; mt < 4; ++mt) {
                const int row  = wm * 64 + mt * 16 + l15;
                const int segl = (kg * 4 + quad) ^ l15;        // row&15 == l15
                af[mt] = *(const bf16x8*)(Alds + row * 256 + segl * 16);
            }
            #pragma unroll
            for (int nt = 0; nt < 2; ++nt) {
                const int pix  = r * 58 + wn * 32 + nt * 16 + l15 + s;  // dead p>=56 reads junk/zeros, never stored
                const int segl = (kg * 4 + quad) ^ (pix & 15);
                bfr[nt] = *(const bf16x8*)(slab + pix * 256 + segl * 16);
            }
            #pragma unroll
            for (int mt = 0; mt < 4; ++mt)
                #pragma unroll
                for (int nt = 0; nt < 2; ++nt)
                    acc[mt][nt] = __builtin_amdgcn_mfma_f32_16x16x32_bf16(
                        af[mt], bfr[nt], acc[mt][nt], 0, 0, 0);
        }
    }

    // ---- epilogue: D[m=quad*4+reg][n=l15]; out (N, C_out, H, W), row y0 ----
    float* obase = out + (size_t)n * (COUT * HW) + y0 * WW;
    #pragma unroll
    for (int nt = 0; nt < 2; ++nt) {
        const int p = wn * 32 + nt * 16 + l15;
        if (p < WW) {
            #pragma unroll
            for (int mt = 0; mt < 4; ++mt) {
                const int co = cobase + wm * 64 + mt * 16 + quad * 4;
                const float4 bv = *(const float4*)(bias + co);
                f32x4 a = acc[mt][nt];
                obase[(size_t)(co + 0) * HW + p] = a[0] + bv.x;
                obase[(size_t)(co + 1) * HW + p] = a[1] + bv.y;
                obase[(size_t)(co + 2) * HW + p] = a[2] + bv.z;
                obase[(size_t)(co + 3) * HW + p] = a[3] + bv.w;
            }
        }
    }
}

extern "C" void kernel_launch(void* const* d_in, const int* in_sizes, int n_in,
                              void* d_out, int out_size, void* d_ws, size_t ws_size,
                              hipStream_t stream) {
    const float* x = (const float*)d_in[0];
    const float* w = (const float*)d_in[1];
    const float* b = (const float*)d_in[2];
    __hip_bfloat16* wt = (__hip_bfloat16*)d_ws;          // 589,824 B

    prep_w<<<dim3(1152), dim3(256), 0, stream>>>(w, wt);
    conv_fused<<<dim3(2 * NIMG * HH), dim3(256), 0, stream>>>(
        x, (const char*)wt, b, (float*)d_out);
}